// Round 8
// baseline (326.658 us; speedup 1.0000x reference)
//
#include <hip/hip_runtime.h>
#include <hip/hip_bf16.h>

#define NT 6
#define BM 256
#define BN 256
#define BK 32
#define SLOT 16384   // shorts per ring slot: A 256x32 + B 256x32

typedef __attribute__((ext_vector_type(4))) float f32x4;
typedef __attribute__((ext_vector_type(8))) short bf16x8;

__device__ __forceinline__ short f2bf(float f) {
    __hip_bfloat16 h = __float2bfloat16(f);
    return (short)__builtin_bit_cast(unsigned short, h);
}

// ---- 1. segment argmax: packed (conf_bits<<32) | ~idx, atomicMax ----
__global__ void k_segmax(const float* __restrict__ conf,
                         const int* __restrict__ bidx,
                         unsigned long long* __restrict__ packed, int E) {
    int i = blockIdx.x * blockDim.x + threadIdx.x;
    if (i >= E) return;
    unsigned cb = __float_as_uint(conf[i]);
    unsigned long long p = ((unsigned long long)cb << 32) | (unsigned)(~(unsigned)i);
    atomicMax(&packed[bidx[i]], p);
}

// ---- 2. base[t][n] = emb[t] . W1[n,:d4] + b1[n]; extract conf/x/y columns ----
__global__ void k_base(const float* __restrict__ emb, const float* __restrict__ W1,
                       const float* __restrict__ b1, float* __restrict__ base,
                       float* __restrict__ vecs, int d2, int d4) {
    int gw = (blockIdx.x * blockDim.x + threadIdx.x) >> 6;
    int lane = threadIdx.x & 63;
    int t = gw / d2, n = gw % d2;
    const float* e = emb + (size_t)t * d4;
    const float* w = W1 + (size_t)n * (d4 + 3);
    float s = 0.f;
    for (int k = lane; k < d4; k += 64) s += e[k] * w[k];
#pragma unroll
    for (int m = 32; m; m >>= 1) s += __shfl_xor(s, m);
    if (lane == 0) {
        base[gw] = s + b1[n];
        if (t == 0) {
            vecs[n]          = w[d4];
            vecs[d2 + n]     = w[d4 + 1];
            vecs[2 * d2 + n] = w[d4 + 2];
        }
    }
}

// ---- 3. W2 fp32 -> bf16 ----
__global__ void k_w2cast(const float* __restrict__ W2, short* __restrict__ W2b, long n) {
    long i = ((long)blockIdx.x * blockDim.x + threadIdx.x) * 8;
    if (i >= n) return;
    bf16x8 v;
#pragma unroll
    for (int j = 0; j < 8; ++j) v[j] = f2bf(W2[i + j]);
    *(bf16x8*)(W2b + i) = v;
}

// ---- 4. h[b][n] = relu(base[t][n] + conf*cv[n] + lx*xv[n] + ly*yv[n]) -> bf16 ----
__global__ void k_h(const unsigned long long* __restrict__ packed,
                    const int* __restrict__ etype, const float* __restrict__ loc,
                    const float* __restrict__ base, const float* __restrict__ vecs,
                    float* __restrict__ mask, short* __restrict__ h, int d2) {
    int b = blockIdx.x;
    int tid = threadIdx.x;
    unsigned long long p = packed[b];
    bool has = (p != 0ULL);
    float conf = 0.f, lx = 0.f, ly = 0.f;
    int t = 0;
    if (has) {
        unsigned idx = ~(unsigned)(p & 0xFFFFFFFFu);
        conf = __uint_as_float((unsigned)(p >> 32));
        t  = etype[idx];
        lx = loc[2 * (size_t)idx]     * (1.0f / 640.0f);
        ly = loc[2 * (size_t)idx + 1] * (1.0f / 480.0f);
    }
    if (tid == 0) mask[b] = has ? 1.0f : 0.0f;
    const float* bs = base + (size_t)t * d2;
    const float* cv = vecs;
    const float* xv = vecs + d2;
    const float* yv = vecs + 2 * d2;
    int n0 = tid * 8;
    bf16x8 v;
#pragma unroll
    for (int j = 0; j < 8; ++j) {
        int n = n0 + j;
        float g = bs[n] + conf * cv[n] + lx * xv[n] + ly * yv[n];
        g = fmaxf(g, 0.f);
        v[j] = has ? f2bf(g) : (short)0;
    }
    *(bf16x8*)(h + (size_t)b * d2 + n0) = v;
}

// ---- 5. GEMM: C[M][N] = A[M][K](bf16) * Bm[N][K](bf16)^T, +b2, *mask ----
// 256x256, BK=32, 4-slot ring, 8 waves (2x4), per-wave 128x64, 16x16x32 MFMA.
// m201-faithful phase structure: per tile 2 phases, each
//   {ds_reads -> GLL -> s_barrier -> lgkmcnt(0) -> setprio(1) 16 MFMA
//    setprio(0) -> s_barrier}
// Reads are issued BEFORE the opening barrier: they drain in the LDS pipe
// while this wave waits at the barrier for siblings still in the previous
// MFMA cluster -> LDS and MFMA pipes overlap across waves.
// vmcnt(8) once per tile before PhB's closing barrier (never drains).
// Swizzle: phys chunk p of row r holds global chunk p^((r>>1)&3) (0-conflict,
// verified R3).

#define GLL(src, dst) __builtin_amdgcn_global_load_lds(                      \
    (const __attribute__((address_space(1))) void*)(src),                    \
    (__attribute__((address_space(3))) void*)(dst), 16, 0, 0)

#define SB __builtin_amdgcn_sched_barrier(0)

__global__ __launch_bounds__(512, 2)
void k_gemm(const short* __restrict__ A, const short* __restrict__ Bm,
            const float* __restrict__ b2, const float* __restrict__ mask,
            float* __restrict__ C, int M, int N, int K, int nbn) {
    __shared__ __align__(16) short lds[4 * SLOT];

    int tid = threadIdx.x;
    int lane = tid & 63;
    int wave = tid >> 6;            // 0..7
    int wr = wave >> 2, wc = wave & 3;

    // XCD-aware bijective swizzle (grid % 8 == 0)
    int bid = blockIdx.x;
    int wg = (bid & 7) * ((int)gridDim.x >> 3) + (bid >> 3);
    int bm = wg / nbn, bn = wg % nbn;
    int row0 = bm * BM, col0 = bn * BN;

    // ---- staging addresses (4 x 16B per thread per K-tile) ----
    int srow = tid >> 2;                            // 0..127
    int chunkL = (tid & 3) ^ ((srow >> 1) & 3);     // inverse-swizzled source
    const short* pa0 = A + (size_t)(row0 + srow) * K + chunkL * 8;
    const short* pa1 = pa0 + (size_t)128 * K;
    const short* pb0 = Bm + (size_t)(col0 + srow) * K + chunkL * 8;
    const short* pb1 = pb0 + (size_t)128 * K;
    int dA0 = tid * 8, dA1 = 4096 + tid * 8;
    int dB0 = 8192 + tid * 8, dB1 = 12288 + tid * 8;

    // ---- fragment read offsets (proven 0-conflict pattern) ----
    int frow = lane & 15, fk = lane >> 4;
    int cp = fk ^ ((frow >> 1) & 3);                // physical chunk
    int aoff = (wr * 128 + frow) * 32 + cp * 8;
    int boff = 8192 + (wc * 64 + frow) * 32 + cp * 8;

    f32x4 acc[8][4] = {};
    bf16x8 a03[4], a47[4], bv[4];

    int KT = K / BK;                                // 64

    // prologue: stage tiles 0,1,2; tile 0 resident after vmcnt(8)+barrier
    {
        short* s0 = lds + 0 * SLOT;
        GLL(pa0, s0 + dA0); GLL(pa1, s0 + dA1); GLL(pb0, s0 + dB0); GLL(pb1, s0 + dB1);
        pa0 += BK; pa1 += BK; pb0 += BK; pb1 += BK;
        short* s1 = lds + 1 * SLOT;
        GLL(pa0, s1 + dA0); GLL(pa1, s1 + dA1); GLL(pb0, s1 + dB0); GLL(pb1, s1 + dB1);
        pa0 += BK; pa1 += BK; pb0 += BK; pb1 += BK;
        short* s2 = lds + 2 * SLOT;
        GLL(pa0, s2 + dA0); GLL(pa1, s2 + dA1); GLL(pb0, s2 + dB0); GLL(pb1, s2 + dB1);
        pa0 += BK; pa1 += BK; pb0 += BK; pb1 += BK;
    }
    asm volatile("s_waitcnt vmcnt(8)" ::: "memory");
    __builtin_amdgcn_s_barrier();

#pragma unroll 1
    for (int t = 0; t < KT; ++t) {
        const short* sr = lds + (t & 3) * SLOT;
        short* sw = lds + ((t + 3) & 3) * SLOT;
        bool stage = (t < KT - 3);

        // ===== Phase A =====
        // reads BEFORE opening barrier: B n0-3 + A m0-3 (8 x b128)
#pragma unroll
        for (int n = 0; n < 4; ++n)
            bv[n] = *(const bf16x8*)(sr + boff + n * 512);
#pragma unroll
        for (int m = 0; m < 4; ++m)
            a03[m] = *(const bf16x8*)(sr + aoff + m * 512);
        if (stage) { GLL(pa0, sw + dA0); GLL(pa1, sw + dA1); }
        SB;
        __builtin_amdgcn_s_barrier();
        asm volatile("s_waitcnt lgkmcnt(0)" ::: "memory");
        SB;
        __builtin_amdgcn_s_setprio(1);
#pragma unroll
        for (int m = 0; m < 4; ++m)
#pragma unroll
            for (int n = 0; n < 4; ++n)
                acc[m][n] = __builtin_amdgcn_mfma_f32_16x16x32_bf16(
                    a03[m], bv[n], acc[m][n], 0, 0, 0);
        __builtin_amdgcn_s_setprio(0);
        SB;
        __builtin_amdgcn_s_barrier();

        // ===== Phase B =====
        // reads BEFORE opening barrier: A m4-7 (4 x b128)
#pragma unroll
        for (int m = 0; m < 4; ++m)
            a47[m] = *(const bf16x8*)(sr + aoff + 2048 + m * 512);
        if (stage) { GLL(pb0, sw + dB0); GLL(pb1, sw + dB1); }
        pa0 += BK; pa1 += BK; pb0 += BK; pb1 += BK;
        SB;
        __builtin_amdgcn_s_barrier();
        asm volatile("s_waitcnt lgkmcnt(0)" ::: "memory");
        SB;
        __builtin_amdgcn_s_setprio(1);
#pragma unroll
        for (int m = 0; m < 4; ++m)
#pragma unroll
            for (int n = 0; n < 4; ++n)
                acc[4 + m][n] = __builtin_amdgcn_mfma_f32_16x16x32_bf16(
                    a47[m], bv[n], acc[4 + m][n], 0, 0, 0);
        __builtin_amdgcn_s_setprio(0);
        SB;
        if (t < KT - 1) {
            // slot t+1 residency guarantee for next tile's Phase-A reads
            if (t < KT - 3)       asm volatile("s_waitcnt vmcnt(8)" ::: "memory");
            else if (t == KT - 3) asm volatile("s_waitcnt vmcnt(4)" ::: "memory");
            else                  asm volatile("s_waitcnt vmcnt(0)" ::: "memory");
            __builtin_amdgcn_s_barrier();
        }
    }

    // ---- epilogue: +b2, *mask ----
#pragma unroll
    for (int m = 0; m < 8; ++m) {
        int rbase = row0 + wr * 128 + m * 16 + (lane >> 4) * 4;
#pragma unroll
        for (int j = 0; j < 4; ++j) {
            int r = rbase + j;
            float mk = mask[r];
#pragma unroll
            for (int n = 0; n < 4; ++n) {
                int c = col0 + wc * 64 + n * 16 + frow;
                C[(size_t)r * N + c] = (acc[m][n][j] + b2[c]) * mk;
            }
        }
    }
}

extern "C" void kernel_launch(void* const* d_in, const int* in_sizes, int n_in,
                              void* d_out, int out_size, void* d_ws, size_t ws_size,
                              hipStream_t stream) {
    const int* etype   = (const int*)d_in[0];
    const float* conf  = (const float*)d_in[1];
    const float* loc   = (const float*)d_in[2];
    const int* bidx    = (const int*)d_in[3];
    const float* emb   = (const float*)d_in[5];
    const float* W1    = (const float*)d_in[6];
    const float* b1    = (const float*)d_in[7];
    const float* W2    = (const float*)d_in[8];
    const float* b2    = (const float*)d_in[9];
    float* out = (float*)d_out;

    int E  = in_sizes[0];
    int d2 = in_sizes[7];           // 2048
    int d  = in_sizes[9];           // 4096
    int d4 = in_sizes[5] / NT;      // 1024
    int B  = out_size / d;          // 16384

    char* ws = (char*)d_ws;
    unsigned long long* packed = (unsigned long long*)ws;     // B*8
    float* mask = (float*)(ws + (size_t)B * 8);               // B*4
    float* base = mask + B;                                   // NT*d2
    float* vecs = base + NT * d2;                             // 3*d2
    short* w2b  = (short*)(vecs + 3 * d2);                    // d*d2 bf16
    short* h    = w2b + (size_t)d * d2;                       // B*d2 bf16

    hipMemsetAsync(packed, 0, (size_t)B * 8, stream);
    k_segmax<<<(E + 255) / 256, 256, 0, stream>>>(conf, bidx, packed, E);
    k_base<<<(NT * d2) / 4, 256, 0, stream>>>(emb, W1, b1, base, vecs, d2, d4);
    long nw2 = (long)d * d2;
    k_w2cast<<<(int)(nw2 / 8 / 256), 256, 0, stream>>>(W2, w2b, nw2);
    k_h<<<B, 256, 0, stream>>>(packed, etype, loc, base, vecs, mask, h, d2);
    int nbm = B / BM, nbn = d / BN;
    k_gemm<<<dim3(nbm * nbn), dim3(512), 0, stream>>>(h, w2b, b2, mask, out, B, d, d2, nbn);
}

// Round 9
// 307.445 us; speedup vs baseline: 1.0625x; 1.0625x over previous
//
#include <hip/hip_runtime.h>
#include <hip/hip_bf16.h>

#define NT 6
#define BM 256
#define BN 256
#define BK 64
#define SLOT_S 32768      // shorts per dbuf slot: (A 256x64 + B 256x64) = 64KB
// slot layout (shorts): A-h0 @0, A-h1 @8192, B-h0 @16384, B-h1 @24576
#define AH1 8192
#define BH0 16384
#define BH1 24576

typedef __attribute__((ext_vector_type(4))) float f32x4;
typedef __attribute__((ext_vector_type(8))) short bf16x8;

__device__ __forceinline__ short f2bf(float f) {
    __hip_bfloat16 h = __float2bfloat16(f);
    return (short)__builtin_bit_cast(unsigned short, h);
}

// ---- 1. segment argmax: packed (conf_bits<<32) | ~idx, atomicMax ----
__global__ void k_segmax(const float* __restrict__ conf,
                         const int* __restrict__ bidx,
                         unsigned long long* __restrict__ packed, int E) {
    int i = blockIdx.x * blockDim.x + threadIdx.x;
    if (i >= E) return;
    unsigned cb = __float_as_uint(conf[i]);
    unsigned long long p = ((unsigned long long)cb << 32) | (unsigned)(~(unsigned)i);
    atomicMax(&packed[bidx[i]], p);
}

// ---- 2. base[t][n] = emb[t] . W1[n,:d4] + b1[n]; extract conf/x/y columns ----
__global__ void k_base(const float* __restrict__ emb, const float* __restrict__ W1,
                       const float* __restrict__ b1, float* __restrict__ base,
                       float* __restrict__ vecs, int d2, int d4) {
    int gw = (blockIdx.x * blockDim.x + threadIdx.x) >> 6;
    int lane = threadIdx.x & 63;
    int t = gw / d2, n = gw % d2;
    const float* e = emb + (size_t)t * d4;
    const float* w = W1 + (size_t)n * (d4 + 3);
    float s = 0.f;
    for (int k = lane; k < d4; k += 64) s += e[k] * w[k];
#pragma unroll
    for (int m = 32; m; m >>= 1) s += __shfl_xor(s, m);
    if (lane == 0) {
        base[gw] = s + b1[n];
        if (t == 0) {
            vecs[n]          = w[d4];
            vecs[d2 + n]     = w[d4 + 1];
            vecs[2 * d2 + n] = w[d4 + 2];
        }
    }
}

// ---- 3. W2 fp32 -> bf16 ----
__global__ void k_w2cast(const float* __restrict__ W2, short* __restrict__ W2b, long n) {
    long i = ((long)blockIdx.x * blockDim.x + threadIdx.x) * 8;
    if (i >= n) return;
    bf16x8 v;
#pragma unroll
    for (int j = 0; j < 8; ++j) v[j] = f2bf(W2[i + j]);
    *(bf16x8*)(W2b + i) = v;
}

// ---- 4. h[b][n] = relu(base[t][n] + conf*cv[n] + lx*xv[n] + ly*yv[n]) -> bf16 ----
__global__ void k_h(const unsigned long long* __restrict__ packed,
                    const int* __restrict__ etype, const float* __restrict__ loc,
                    const float* __restrict__ base, const float* __restrict__ vecs,
                    float* __restrict__ mask, short* __restrict__ h, int d2) {
    int b = blockIdx.x;
    int tid = threadIdx.x;
    unsigned long long p = packed[b];
    bool has = (p != 0ULL);
    float conf = 0.f, lx = 0.f, ly = 0.f;
    int t = 0;
    if (has) {
        unsigned idx = ~(unsigned)(p & 0xFFFFFFFFu);
        conf = __uint_as_float((unsigned)(p >> 32));
        t  = etype[idx];
        lx = loc[2 * (size_t)idx]     * (1.0f / 640.0f);
        ly = loc[2 * (size_t)idx + 1] * (1.0f / 480.0f);
    }
    if (tid == 0) mask[b] = has ? 1.0f : 0.0f;
    const float* bs = base + (size_t)t * d2;
    const float* cv = vecs;
    const float* xv = vecs + d2;
    const float* yv = vecs + 2 * d2;
    int n0 = tid * 8;
    bf16x8 v;
#pragma unroll
    for (int j = 0; j < 8; ++j) {
        int n = n0 + j;
        float g = bs[n] + conf * cv[n] + lx * xv[n] + ly * yv[n];
        g = fmaxf(g, 0.f);
        v[j] = has ? f2bf(g) : (short)0;
    }
    *(bf16x8*)(h + (size_t)b * d2 + n0) = v;
}

// ---- 5. GEMM: m201-style 8-phase/2-tile structure, adapted ----
// 256x256, BK=64, 2-slot dbuf (128 KiB), 8 waves (2x4), per-wave 128x64
// (rows wr*64 + mh*128, cols wc*32 + nh*128). 4 phases/tile, quadrants
// (mh,nh) = (0,0),(0,1),(1,1),(1,0). B frags held in regs all tile.
// Staging: one/two 16KB half-tile units per phase into the other slot:
//   ph0: A-h0(t+1)+B-h0(t+1)   ph1: B-h1(t+1)   ph2: A-h1(t+1)
// Waits (counted, never drain; retire exactly what the next phase reads):
//   ph0 end: vmcnt(6)  [retires B-h1(t), issued t-1.ph1; 6 = Ah1(t)2+ph0's 4]
//   ph1 end: vmcnt(6)  [retires A-h1(t); 6 = ph0's 4 + ph1's 2]
//   ph2 end: no wait/barrier (ph3 reads nothing)
//   ph3 end: vmcnt(4)  [retires Ah0,Bh0(t+1); 4 = Bh1(t+1)+Ah1(t+1)]
// LDS swizzle (128B rows -> all rows bank-aligned): granule p of row r
// holds global k-chunk p^(r&7); 8-lane read groups hit 32 distinct banks.
// GLL dest linear (tid*16B), source pre-inverse-swizzled (rule #21).

#define GLL(src, dst) __builtin_amdgcn_global_load_lds(                      \
    (const __attribute__((address_space(1))) void*)(src),                    \
    (__attribute__((address_space(3))) void*)(dst), 16, 0, 0)

#define SB __builtin_amdgcn_sched_barrier(0)

#define ST_AH0(ws, kt) { GLL(pA + (size_t)(kt) * 64, (ws) + dst1);           \
                         GLL(pA + (size_t)64 * K + (kt) * 64, (ws) + dst2); }
#define ST_AH1(ws, kt) { GLL(pA + (size_t)128 * K + (kt) * 64, (ws) + AH1 + dst1); \
                         GLL(pA + (size_t)192 * K + (kt) * 64, (ws) + AH1 + dst2); }
#define ST_BH0(ws, kt) { GLL(pB + (size_t)(kt) * 64, (ws) + BH0 + dst1);     \
                         GLL(pB + (size_t)64 * K + (kt) * 64, (ws) + BH0 + dst2); }
#define ST_BH1(ws, kt) { GLL(pB + (size_t)128 * K + (kt) * 64, (ws) + BH1 + dst1); \
                         GLL(pB + (size_t)192 * K + (kt) * 64, (ws) + BH1 + dst2); }

#define MFMA16(AI, NI, BVV)                                                  \
    _Pragma("unroll") for (int m = 0; m < 4; ++m)                            \
    _Pragma("unroll") for (int n = 0; n < 2; ++n) {                          \
        acc[(AI) + m][(NI) + n] = __builtin_amdgcn_mfma_f32_16x16x32_bf16(   \
            aA[m][0], BVV[n][0], acc[(AI) + m][(NI) + n], 0, 0, 0);          \
        acc[(AI) + m][(NI) + n] = __builtin_amdgcn_mfma_f32_16x16x32_bf16(   \
            aA[m][1], BVV[n][1], acc[(AI) + m][(NI) + n], 0, 0, 0);          \
    }

__global__ __launch_bounds__(512, 2)
void k_gemm(const short* __restrict__ A, const short* __restrict__ Bm,
            const float* __restrict__ b2, const float* __restrict__ mask,
            float* __restrict__ C, int M, int N, int K, int nbn) {
    __shared__ __align__(16) short lds[2 * SLOT_S];   // 128 KiB

    int tid = threadIdx.x;
    int lane = tid & 63;
    int wave = tid >> 6;            // 0..7
    int wr = wave >> 2, wc = wave & 3;

    // XCD-aware bijective swizzle (grid = 1024, % 8 == 0)
    int bid = blockIdx.x;
    int wg = (bid & 7) * ((int)gridDim.x >> 3) + (bid >> 3);
    int bm = wg / nbn, bn = wg % nbn;
    int row0 = bm * BM, col0 = bn * BN;

    // ---- staging precompute: thread covers granules tid and tid+512 ----
    int r1 = tid >> 3;                         // 0..63
    int pg = tid & 7;
    int cg = pg ^ (r1 & 7);                    // inverse-swizzled source chunk
    const short* pA = A + (size_t)(row0 + r1) * K + cg * 8;
    const short* pB = Bm + (size_t)(col0 + r1) * K + cg * 8;
    int dst1 = tid * 8;                        // shorts (tid*16 bytes)
    int dst2 = 4096 + tid * 8;                 // rows 64..127 of the unit

    // ---- fragment read offsets ----
    int frow = lane & 15, fk = lane >> 4;
    int kx = frow & 7;
    int aoffs0 = (wr * 64 + frow) * 64 + ((fk) ^ kx) * 8;        // k-step 0
    int aoffs1 = (wr * 64 + frow) * 64 + ((4 + fk) ^ kx) * 8;    // k-step 1
    int boffs0 = (wc * 32 + frow) * 64 + ((fk) ^ kx) * 8;
    int boffs1 = (wc * 32 + frow) * 64 + ((4 + fk) ^ kx) * 8;

    f32x4 acc[8][4] = {};
    bf16x8 aA[4][2], bB0[2][2], bB1[2][2];

    int KT = K / BK;                           // 32

    // ---- prologue: stage tile 0 fully into slot 0, drain once ----
    ST_AH0(lds, 0); ST_BH0(lds, 0); ST_BH1(lds, 0); ST_AH1(lds, 0);
    asm volatile("s_waitcnt vmcnt(0)" ::: "memory");
    __builtin_amdgcn_s_barrier();
    SB;

#pragma unroll 1
    for (int t = 0; t < KT; ++t) {
        const short* sl = lds + (t & 1) * SLOT_S;
        short* wsl = lds + ((t + 1) & 1) * SLOT_S;
        bool stg = (t < KT - 1);

        // ===== ph0: quadrant (mh0, nh0) =====
#pragma unroll
        for (int n = 0; n < 2; ++n) {
            bB0[n][0] = *(const bf16x8*)(sl + BH0 + boffs0 + n * 1024);
            bB0[n][1] = *(const bf16x8*)(sl + BH0 + boffs1 + n * 1024);
        }
#pragma unroll
        for (int m = 0; m < 4; ++m) {
            aA[m][0] = *(const bf16x8*)(sl + aoffs0 + m * 1024);
            aA[m][1] = *(const bf16x8*)(sl + aoffs1 + m * 1024);
        }
        if (stg) { ST_AH0(wsl, t + 1); ST_BH0(wsl, t + 1); }
        SB;
        __builtin_amdgcn_s_barrier();
        asm volatile("s_waitcnt lgkmcnt(0)" ::: "memory");
        SB;
        __builtin_amdgcn_s_setprio(1);
        MFMA16(0, 0, bB0)
        __builtin_amdgcn_s_setprio(0);
        SB;
        if (stg) asm volatile("s_waitcnt vmcnt(6)" ::: "memory");
        else     asm volatile("s_waitcnt vmcnt(2)" ::: "memory");
        __builtin_amdgcn_s_barrier();

        // ===== ph1: quadrant (mh0, nh1) =====
#pragma unroll
        for (int n = 0; n < 2; ++n) {
            bB1[n][0] = *(const bf16x8*)(sl + BH1 + boffs0 + n * 1024);
            bB1[n][1] = *(const bf16x8*)(sl + BH1 + boffs1 + n * 1024);
        }
        if (stg) ST_BH1(wsl, t + 1);
        SB;
        __builtin_amdgcn_s_barrier();
        asm volatile("s_waitcnt lgkmcnt(0)" ::: "memory");
        SB;
        __builtin_amdgcn_s_setprio(1);
        MFMA16(0, 2, bB1)
        __builtin_amdgcn_s_setprio(0);
        SB;
        if (stg) asm volatile("s_waitcnt vmcnt(6)" ::: "memory");
        else     asm volatile("s_waitcnt vmcnt(0)" ::: "memory");
        __builtin_amdgcn_s_barrier();

        // ===== ph2: quadrant (mh1, nh1) =====
#pragma unroll
        for (int m = 0; m < 4; ++m) {
            aA[m][0] = *(const bf16x8*)(sl + AH1 + aoffs0 + m * 1024);
            aA[m][1] = *(const bf16x8*)(sl + AH1 + aoffs1 + m * 1024);
        }
        if (stg) ST_AH1(wsl, t + 1);
        SB;
        __builtin_amdgcn_s_barrier();
        asm volatile("s_waitcnt lgkmcnt(0)" ::: "memory");
        SB;
        __builtin_amdgcn_s_setprio(1);
        MFMA16(4, 2, bB1)
        __builtin_amdgcn_s_setprio(0);
        SB;

        // ===== ph3: quadrant (mh1, nh0) — register-only, no barrier in ====
        __builtin_amdgcn_s_setprio(1);
        MFMA16(4, 0, bB0)
        __builtin_amdgcn_s_setprio(0);
        SB;
        if (stg) {
            asm volatile("s_waitcnt vmcnt(4)" ::: "memory");
            __builtin_amdgcn_s_barrier();
            SB;
        }
    }

    // ---- epilogue: +b2, *mask ----
#pragma unroll
    for (int mi = 0; mi < 8; ++mi) {
        int rbase = row0 + (mi >> 2) * 128 + wr * 64 + (mi & 3) * 16 + fk * 4;
#pragma unroll
        for (int j = 0; j < 4; ++j) {
            int r = rbase + j;
            float mk = mask[r];
#pragma unroll
            for (int ni = 0; ni < 4; ++ni) {
                int cc = col0 + (ni >> 1) * 128 + wc * 32 + (ni & 1) * 16 + frow;
                C[(size_t)r * N + cc] = (acc[mi][ni][j] + b2[cc]) * mk;
            }
        }
    }
}

extern "C" void kernel_launch(void* const* d_in, const int* in_sizes, int n_in,
                              void* d_out, int out_size, void* d_ws, size_t ws_size,
                              hipStream_t stream) {
    const int* etype   = (const int*)d_in[0];
    const float* conf  = (const float*)d_in[1];
    const float* loc   = (const float*)d_in[2];
    const int* bidx    = (const int*)d_in[3];
    const float* emb   = (const float*)d_in[5];
    const float* W1    = (const float*)d_in[6];
    const float* b1    = (const float*)d_in[7];
    const float* W2    = (const float*)d_in[8];
    const float* b2    = (const float*)d_in[9];
    float* out = (float*)d_out;

    int E  = in_sizes[0];
    int d2 = in_sizes[7];           // 2048
    int d  = in_sizes[9];           // 4096
    int d4 = in_sizes[5] / NT;      // 1024
    int B  = out_size / d;          // 16384

    char* ws = (char*)d_ws;
    unsigned long long* packed = (unsigned long long*)ws;     // B*8
    float* mask = (float*)(ws + (size_t)B * 8);               // B*4
    float* base = mask + B;                                   // NT*d2
    float* vecs = base + NT * d2;                             // 3*d2
    short* w2b  = (short*)(vecs + 3 * d2);                    // d*d2 bf16
    short* h    = w2b + (size_t)d * d2;                       // B*d2 bf16

    hipMemsetAsync(packed, 0, (size_t)B * 8, stream);
    k_segmax<<<(E + 255) / 256, 256, 0, stream>>>(conf, bidx, packed, E);
    k_base<<<(NT * d2) / 4, 256, 0, stream>>>(emb, W1, b1, base, vecs, d2, d4);
    long nw2 = (long)d * d2;
    k_w2cast<<<(int)(nw2 / 8 / 256), 256, 0, stream>>>(W2, w2b, nw2);
    k_h<<<B, 256, 0, stream>>>(packed, etype, loc, base, vecs, mask, h, d2);
    int nbm = B / BM, nbn = d / BN;
    k_gemm<<<dim3(nbm * nbn), dim3(512), 0, stream>>>(h, w2b, b2, mask, out, B, d, d2, nbn);
}

// Round 10
// 295.562 us; speedup vs baseline: 1.1052x; 1.0402x over previous
//
#include <hip/hip_runtime.h>
#include <hip/hip_bf16.h>

#define NT 6
#define BM 256
#define BN 256
#define BK 64
#define SLOT_S 32768      // shorts per dbuf slot: (A 256x64 + B 256x64) = 64KB
// slot layout (shorts): A-h0 @0 (rows 0-127), A-h1 @8192 (rows 128-255),
//                       B-h0 @16384, B-h1 @24576
#define AH1 8192
#define BH0 16384
#define BH1 24576

typedef __attribute__((ext_vector_type(4))) float f32x4;
typedef __attribute__((ext_vector_type(8))) short bf16x8;

__device__ __forceinline__ short f2bf(float f) {
    __hip_bfloat16 h = __float2bfloat16(f);
    return (short)__builtin_bit_cast(unsigned short, h);
}

// ---- 1. segment argmax: packed (conf_bits<<32) | ~idx, atomicMax ----
__global__ void k_segmax(const float* __restrict__ conf,
                         const int* __restrict__ bidx,
                         unsigned long long* __restrict__ packed, int E) {
    int i = blockIdx.x * blockDim.x + threadIdx.x;
    if (i >= E) return;
    unsigned cb = __float_as_uint(conf[i]);
    unsigned long long p = ((unsigned long long)cb << 32) | (unsigned)(~(unsigned)i);
    atomicMax(&packed[bidx[i]], p);
}

// ---- 2. base[t][n] = emb[t] . W1[n,:d4] + b1[n]; extract conf/x/y columns ----
__global__ void k_base(const float* __restrict__ emb, const float* __restrict__ W1,
                       const float* __restrict__ b1, float* __restrict__ base,
                       float* __restrict__ vecs, int d2, int d4) {
    int gw = (blockIdx.x * blockDim.x + threadIdx.x) >> 6;
    int lane = threadIdx.x & 63;
    int t = gw / d2, n = gw % d2;
    const float* e = emb + (size_t)t * d4;
    const float* w = W1 + (size_t)n * (d4 + 3);
    float s = 0.f;
    for (int k = lane; k < d4; k += 64) s += e[k] * w[k];
#pragma unroll
    for (int m = 32; m; m >>= 1) s += __shfl_xor(s, m);
    if (lane == 0) {
        base[gw] = s + b1[n];
        if (t == 0) {
            vecs[n]          = w[d4];
            vecs[d2 + n]     = w[d4 + 1];
            vecs[2 * d2 + n] = w[d4 + 2];
        }
    }
}

// ---- 3. W2 fp32 -> bf16 ----
__global__ void k_w2cast(const float* __restrict__ W2, short* __restrict__ W2b, long n) {
    long i = ((long)blockIdx.x * blockDim.x + threadIdx.x) * 8;
    if (i >= n) return;
    bf16x8 v;
#pragma unroll
    for (int j = 0; j < 8; ++j) v[j] = f2bf(W2[i + j]);
    *(bf16x8*)(W2b + i) = v;
}

// ---- 4. h[b][n] = relu(base[t][n] + conf*cv[n] + lx*xv[n] + ly*yv[n]) -> bf16 ----
__global__ void k_h(const unsigned long long* __restrict__ packed,
                    const int* __restrict__ etype, const float* __restrict__ loc,
                    const float* __restrict__ base, const float* __restrict__ vecs,
                    float* __restrict__ mask, short* __restrict__ h, int d2) {
    int b = blockIdx.x;
    int tid = threadIdx.x;
    unsigned long long p = packed[b];
    bool has = (p != 0ULL);
    float conf = 0.f, lx = 0.f, ly = 0.f;
    int t = 0;
    if (has) {
        unsigned idx = ~(unsigned)(p & 0xFFFFFFFFu);
        conf = __uint_as_float((unsigned)(p >> 32));
        t  = etype[idx];
        lx = loc[2 * (size_t)idx]     * (1.0f / 640.0f);
        ly = loc[2 * (size_t)idx + 1] * (1.0f / 480.0f);
    }
    if (tid == 0) mask[b] = has ? 1.0f : 0.0f;
    const float* bs = base + (size_t)t * d2;
    const float* cv = vecs;
    const float* xv = vecs + d2;
    const float* yv = vecs + 2 * d2;
    int n0 = tid * 8;
    bf16x8 v;
#pragma unroll
    for (int j = 0; j < 8; ++j) {
        int n = n0 + j;
        float g = bs[n] + conf * cv[n] + lx * xv[n] + ly * yv[n];
        g = fmaxf(g, 0.f);
        v[j] = has ? f2bf(g) : (short)0;
    }
    *(bf16x8*)(h + (size_t)b * d2 + n0) = v;
}

// ---- 5. GEMM: single-mega-phase per K64 tile ----
// 256x256, BK=64, 2-slot dbuf (128 KiB), 8 waves (2x4), 16x16x32 MFMA.
// Per K64 tile: {24 ds_read_b128 (whole tile's frags -> 96 VGPR);
// 8 GLL staging t+1 into other slot; 64 MFMA in ONE cluster (compiler
// interleaves counted lgkm waits); vmcnt(0); barrier}. One barrier, one
// vm-drain, one lgkm-chain per 2484 MFMA-cycles — the per-phase drain
// stall that pinned R3..R9 at 39-43% MfmaUtil amortizes 2-4x deeper.
// drain-0 safe: GLLs issue at tile top, land under the 64-MFMA cluster.
// WAR safe: tile t writes slot (t+1)&1, whose readers (tile t-1) finished
// before t-1's closing barrier. Swizzle/staging/epilogue = R9 (verified:
// 0 conflicts, absmax 0.0156).

#define GLL(src, dst) __builtin_amdgcn_global_load_lds(                      \
    (const __attribute__((address_space(1))) void*)(src),                    \
    (__attribute__((address_space(3))) void*)(dst), 16, 0, 0)

#define ST_AH0(ws, kt) { GLL(pA + (size_t)(kt) * 64, (ws) + dst1);           \
                         GLL(pA + (size_t)64 * K + (kt) * 64, (ws) + dst2); }
#define ST_AH1(ws, kt) { GLL(pA + (size_t)128 * K + (kt) * 64, (ws) + AH1 + dst1); \
                         GLL(pA + (size_t)192 * K + (kt) * 64, (ws) + AH1 + dst2); }
#define ST_BH0(ws, kt) { GLL(pB + (size_t)(kt) * 64, (ws) + BH0 + dst1);     \
                         GLL(pB + (size_t)64 * K + (kt) * 64, (ws) + BH0 + dst2); }
#define ST_BH1(ws, kt) { GLL(pB + (size_t)128 * K + (kt) * 64, (ws) + BH1 + dst1); \
                         GLL(pB + (size_t)192 * K + (kt) * 64, (ws) + BH1 + dst2); }

__global__ __launch_bounds__(512, 2)
void k_gemm(const short* __restrict__ A, const short* __restrict__ Bm,
            const float* __restrict__ b2, const float* __restrict__ mask,
            float* __restrict__ C, int M, int N, int K, int nbn) {
    __shared__ __align__(16) short lds[2 * SLOT_S];   // 128 KiB

    int tid = threadIdx.x;
    int lane = tid & 63;
    int wave = tid >> 6;            // 0..7
    int wr = wave >> 2, wc = wave & 3;

    // XCD-aware bijective swizzle (grid = 1024, % 8 == 0)
    int bid = blockIdx.x;
    int wg = (bid & 7) * ((int)gridDim.x >> 3) + (bid >> 3);
    int bm = wg / nbn, bn = wg % nbn;
    int row0 = bm * BM, col0 = bn * BN;

    // ---- staging precompute (R9, verified) ----
    int r1 = tid >> 3;                         // 0..63
    int pg = tid & 7;
    int cg = pg ^ (r1 & 7);                    // inverse-swizzled source chunk
    const short* pA = A + (size_t)(row0 + r1) * K + cg * 8;
    const short* pB = Bm + (size_t)(col0 + r1) * K + cg * 8;
    int dst1 = tid * 8;
    int dst2 = 4096 + tid * 8;

    // ---- fragment read offsets (R9, verified 0-conflict) ----
    int frow = lane & 15, fk = lane >> 4;
    int kx = frow & 7;
    int aoffs0 = (wr * 64 + frow) * 64 + ((fk) ^ kx) * 8;
    int aoffs1 = (wr * 64 + frow) * 64 + ((4 + fk) ^ kx) * 8;
    int boffs0 = (wc * 32 + frow) * 64 + ((fk) ^ kx) * 8;
    int boffs1 = (wc * 32 + frow) * 64 + ((4 + fk) ^ kx) * 8;

    f32x4 acc[8][4] = {};
    bf16x8 aA[8][2], bB[4][2];

    int KT = K / BK;                           // 32

    // ---- prologue: stage tile 0 into slot 0, drain once ----
    ST_AH0(lds, 0); ST_BH0(lds, 0); ST_BH1(lds, 0); ST_AH1(lds, 0);
    asm volatile("s_waitcnt vmcnt(0)" ::: "memory");
    __builtin_amdgcn_s_barrier();

#pragma unroll 1
    for (int t = 0; t < KT; ++t) {
        const short* sl = lds + (t & 1) * SLOT_S;
        short* wsl = lds + ((t + 1) & 1) * SLOT_S;

        // ---- 24 ds_read_b128: whole tile's fragments to registers ----
#pragma unroll
        for (int m = 0; m < 4; ++m) {
            aA[m][0]     = *(const bf16x8*)(sl + aoffs0 + m * 1024);
            aA[m][1]     = *(const bf16x8*)(sl + aoffs1 + m * 1024);
        }
#pragma unroll
        for (int n = 0; n < 2; ++n) {
            bB[n][0]     = *(const bf16x8*)(sl + BH0 + boffs0 + n * 1024);
            bB[n][1]     = *(const bf16x8*)(sl + BH0 + boffs1 + n * 1024);
            bB[2 + n][0] = *(const bf16x8*)(sl + BH1 + boffs0 + n * 1024);
            bB[2 + n][1] = *(const bf16x8*)(sl + BH1 + boffs1 + n * 1024);
        }
#pragma unroll
        for (int m = 0; m < 4; ++m) {
            aA[4 + m][0] = *(const bf16x8*)(sl + AH1 + aoffs0 + m * 1024);
            aA[4 + m][1] = *(const bf16x8*)(sl + AH1 + aoffs1 + m * 1024);
        }

        // ---- stage tile t+1 (8 GLL) — lands under the MFMA cluster ----
        if (t < KT - 1) {
            ST_AH0(wsl, t + 1); ST_BH0(wsl, t + 1);
            ST_BH1(wsl, t + 1); ST_AH1(wsl, t + 1);
        }

        // ---- 64 MFMA, one cluster ----
        __builtin_amdgcn_s_setprio(1);
#pragma unroll
        for (int m = 0; m < 8; ++m)
#pragma unroll
            for (int n = 0; n < 4; ++n) {
                acc[m][n] = __builtin_amdgcn_mfma_f32_16x16x32_bf16(
                    aA[m][0], bB[n][0], acc[m][n], 0, 0, 0);
                acc[m][n] = __builtin_amdgcn_mfma_f32_16x16x32_bf16(
                    aA[m][1], bB[n][1], acc[m][n], 0, 0, 0);
            }
        __builtin_amdgcn_s_setprio(0);

        if (t < KT - 1) {
            asm volatile("s_waitcnt vmcnt(0)" ::: "memory");
            __builtin_amdgcn_s_barrier();
        }
    }

    // ---- epilogue: +b2, *mask (R9 mapping, verified) ----
#pragma unroll
    for (int mi = 0; mi < 8; ++mi) {
        int rbase = row0 + (mi >> 2) * 128 + wr * 64 + (mi & 3) * 16 + fk * 4;
#pragma unroll
        for (int j = 0; j < 4; ++j) {
            int r = rbase + j;
            float mk = mask[r];
#pragma unroll
            for (int ni = 0; ni < 4; ++ni) {
                int cc = col0 + (ni >> 1) * 128 + wc * 32 + (ni & 1) * 16 + frow;
                C[(size_t)r * N + cc] = (acc[mi][ni][j] + b2[cc]) * mk;
            }
        }
    }
}

extern "C" void kernel_launch(void* const* d_in, const int* in_sizes, int n_in,
                              void* d_out, int out_size, void* d_ws, size_t ws_size,
                              hipStream_t stream) {
    const int* etype   = (const int*)d_in[0];
    const float* conf  = (const float*)d_in[1];
    const float* loc   = (const float*)d_in[2];
    const int* bidx    = (const int*)d_in[3];
    const float* emb   = (const float*)d_in[5];
    const float* W1    = (const float*)d_in[6];
    const float* b1    = (const float*)d_in[7];
    const float* W2    = (const float*)d_in[8];
    const float* b2    = (const float*)d_in[9];
    float* out = (float*)d_out;

    int E  = in_sizes[0];
    int d2 = in_sizes[7];           // 2048
    int d  = in_sizes[9];           // 4096
    int d4 = in_sizes[5] / NT;      // 1024
    int B  = out_size / d;          // 16384

    char* ws = (char*)d_ws;
    unsigned long long* packed = (unsigned long long*)ws;     // B*8
    float* mask = (float*)(ws + (size_t)B * 8);               // B*4
    float* base = mask + B;                                   // NT*d2
    float* vecs = base + NT * d2;                             // 3*d2
    short* w2b  = (short*)(vecs + 3 * d2);                    // d*d2 bf16
    short* h    = w2b + (size_t)d * d2;                       // B*d2 bf16

    hipMemsetAsync(packed, 0, (size_t)B * 8, stream);
    k_segmax<<<(E + 255) / 256, 256, 0, stream>>>(conf, bidx, packed, E);
    k_base<<<(NT * d2) / 4, 256, 0, stream>>>(emb, W1, b1, base, vecs, d2, d4);
    long nw2 = (long)d * d2;
    k_w2cast<<<(int)(nw2 / 8 / 256), 256, 0, stream>>>(W2, w2b, nw2);
    k_h<<<B, 256, 0, stream>>>(packed, etype, loc, base, vecs, mask, h, d2);
    int nbm = B / BM, nbn = d / BN;
    k_gemm<<<dim3(nbm * nbn), dim3(512), 0, stream>>>(h, w2b, b2, mask, out, B, d, d2, nbn);
}